// Round 8
// baseline (149.144 us; speedup 1.0000x reference)
//
#include <hip/hip_runtime.h>
#include <hip/hip_bf16.h>

#define T_TOK 8192
#define DIN   4096
#define DOUT  4096
#define RANK  64
#define NAD   8
#define TS    32          // tokens per tile
#define MAXTILES 264      // sum ceil(count_a/TS) <= 256+7
#define TOTR  (NAD*RANK)  // 512
#define KSPLIT 4
#define KCH   (DIN / KSPLIT)   // 1024
#define NT    (KCH / 64)       // 16 K-steps of BK=64
#define DSPLIT 8
#define DCH   (DOUT / DSPLIT)  // 512
#define NS    (DCH / 64)       // 8 d-steps of 64

typedef __bf16 bf16x8 __attribute__((ext_vector_type(8)));
typedef __bf16 bf16x4 __attribute__((ext_vector_type(4)));
typedef float  f32x4  __attribute__((ext_vector_type(4)));

// ---- workspace layout (bytes) ----
#define WS_CURSORS 0         // 8 int
#define WS_NTILES  64        // 1 int
#define WS_FLAG    128       // 1 int (ids are int64?)
#define WS_TINFO   256       // MAXTILES*3 int
#define WS_PERM    4096      // 8192 int
#define WS_XA      0x10000   // 8192*64 bf16 (1 MB)
#define WS_ABF     0x110000  // 512*4096 bf16 (4 MB)
#define WS_BT      0x510000  // 4096*512 bf16 (4 MB)
#define WS_XAP     0x910000  // KSPLIT*8192*64 fp32 (8 MB)
#define WS_END     (0x910000 + (size_t)KSPLIT * T_TOK * RANK * 4)

__device__ __forceinline__ void gll16(const void* g, void* l) {
  __builtin_amdgcn_global_load_lds(
      (const __attribute__((address_space(1))) unsigned int*)g,
      (__attribute__((address_space(3))) unsigned int*)l, 16, 0, 0);
}

// ---------------- prep: histogram + offsets + tile table ----------------
__global__ __launch_bounds__(1024) void hist_prep(const int* __restrict__ ids,
    int* __restrict__ cursors, int* __restrict__ ntilesp,
    int* __restrict__ flagp, int* __restrict__ tinfo) {
  __shared__ int cnt[NAD];
  __shared__ int s_ofs[NAD], s_tbase[NAD + 1];
  __shared__ int s_is64;
  int tid = threadIdx.x, lane = tid & 63;
  if (tid < NAD) cnt[tid] = 0;
  if (tid == 0) s_is64 = 1;
  __syncthreads();
  // int64 detection: values are 0..7, so if data is i64 every odd 32-bit word is 0
  int any = 0;
  for (int i = tid; i < T_TOK; i += 1024)
    if (i & 1) any |= ids[i];
  if (any) s_is64 = 0;
  __syncthreads();
  int is64 = s_is64;
  int loc[NAD];
#pragma unroll
  for (int a = 0; a < NAD; ++a) loc[a] = 0;
  for (int t = tid; t < T_TOK; t += 1024) {
    int id = (is64 ? ids[2 * t] : ids[t]) & 7;
#pragma unroll
    for (int a = 0; a < NAD; ++a) {
      unsigned long long m = __ballot(id == a);
      if (lane == 0) loc[a] += __popcll(m);
    }
  }
  if (lane == 0) {
#pragma unroll
    for (int a = 0; a < NAD; ++a) if (loc[a]) atomicAdd(&cnt[a], loc[a]);
  }
  __syncthreads();
  if (tid == 0) {
    *flagp = is64;
    int ofs = 0, tb = 0;
    for (int a = 0; a < NAD; ++a) {
      s_ofs[a] = ofs; cursors[a] = ofs;
      s_tbase[a] = tb;
      ofs += cnt[a];
      tb += (cnt[a] + TS - 1) / TS;
    }
    s_tbase[NAD] = tb;
    *ntilesp = tb;
  }
  __syncthreads();
  int ntt = s_tbase[NAD];
  for (int e = tid; e < ntt; e += 1024) {
    int a = 0;
    while (e >= s_tbase[a + 1]) ++a;
    int t0 = (e - s_tbase[a]) * TS;
    int c = cnt[a];
    tinfo[e * 3 + 0] = a;
    tinfo[e * 3 + 1] = s_ofs[a] + t0;
    tinfo[e * 3 + 2] = (c - t0 < TS) ? (c - t0) : TS;
  }
}

// ---------------- scatter tokens into per-adapter groups (wave-aggregated atomics) ----------------
__global__ __launch_bounds__(256) void scatter_k(const int* __restrict__ ids,
    const int* __restrict__ flagp, int* __restrict__ cursors, int* __restrict__ perm) {
  int t = blockIdx.x * 256 + threadIdx.x;
  int lane = threadIdx.x & 63;
  int id = ((*flagp) ? ids[2 * t] : ids[t]) & 7;
  unsigned long long lt = (1ull << lane) - 1ull;
#pragma unroll
  for (int a = 0; a < NAD; ++a) {
    unsigned long long m = __ballot(id == a);
    if (m) {
      int leader = __ffsll((long long)m) - 1;
      int base_a = 0;
      if (lane == leader) base_a = atomicAdd(&cursors[a], __popcll(m));
      base_a = __shfl(base_a, leader, 64);
      if (id == a) perm[base_a + __popcll(m & lt)] = t;
    }
  }
}

// ---------------- merged prep: A fp32->bf16 (2048 blocks) + B transpose (512 blocks) ------------
__global__ __launch_bounds__(256) void prep_ab(const float* __restrict__ A,
    __bf16* __restrict__ Abf, const float* __restrict__ B, __bf16* __restrict__ Bt) {
  if (blockIdx.x < 2048) {
    int i = blockIdx.x * 256 + threadIdx.x;        // TOTR*DIN/4 elements
    float4 v = ((const float4*)A)[i];
    bf16x4 o = { (__bf16)v.x, (__bf16)v.y, (__bf16)v.z, (__bf16)v.w };
    ((bf16x4*)Abf)[i] = o;
  } else {
    __shared__ float t[64][65];
    int idx = blockIdx.x - 2048;
    int rb = idx & 7, db = idx >> 3;
    int tid = threadIdx.x;
    int c = tid & 63, q = tid >> 6;                // q: 0..3
#pragma unroll
    for (int i = 0; i < 16; ++i) {
      int r = i * 4 + q;
      t[r][c] = B[(size_t)(rb * 64 + r) * DOUT + db * 64 + c];
    }
    __syncthreads();
#pragma unroll
    for (int i = 0; i < 16; ++i) {
      int d = i * 4 + q;
      Bt[(size_t)(db * 64 + d) * TOTR + rb * 64 + c] = (__bf16)t[c][d];
    }
  }
}

#define CVT8(lo, hi) { (__bf16)lo.x, (__bf16)lo.y, (__bf16)lo.z, (__bf16)lo.w, \
                       (__bf16)hi.x, (__bf16)hi.y, (__bf16)hi.z, (__bf16)hi.w }

// ---------------- stage 1 (split-K, quad-buffered depth-3 pipeline) ----------------
// grid (MAXTILES, KSPLIT), block 512 (8 waves). 16 K-steps of BK=64.
// Per step: vmcnt(N) -> barrier -> issue stage t+3 -> ds_read+MFMA. ONE barrier/step.
// Queue is pure loads; steady state 6 outstanding -> vmcnt(4) waits exactly step t's
// 2 stages (issued 3 steps = ~600+ cyc earlier). Hazard: issue targets buf[(t+3)&3]
// = buf[(t-1)&3], whose readers all finished before this step's barrier.
__global__ __launch_bounds__(512) void stage1s(const float* __restrict__ x,
    const __bf16* __restrict__ Abf, const int* __restrict__ tinfo,
    const int* __restrict__ ntilesp, const int* __restrict__ perm,
    float* __restrict__ xap) {
  __shared__ char lds[4][16384];   // per buf: [0,8192) = x tile, [8192,16384) = A tile
  int b = blockIdx.x;
  if (b >= *ntilesp) return;       // uniform
  int ks = blockIdx.y;
  int a = tinfo[b * 3], start = tinfo[b * 3 + 1], nv = tinfo[b * 3 + 2];
  int tid = threadIdx.x, lane = tid & 63, wv = tid >> 6;

  // ---- staging addresses (constant across K-steps) ----
  int xr = wv * 4 + (lane >> 4);                       // x row this lane stages
  int xtok = (xr < nv) ? perm[start + xr] : perm[start];
  int xinner = ((lane & 15) * 16) ^ ((xr & 7) << 4);   // swizzled source inner bytes
  const char* xsrc = (const char*)(x + (size_t)xtok * DIN + ks * KCH) + xinner;
  int ar = wv * 8 + (lane >> 3);                       // A row this lane stages
  int ainner = ((lane & 7) * 16) ^ ((ar & 7) << 4);
  const char* asrc = (const char*)(Abf + (size_t)(a * RANK + ar) * DIN + ks * KCH) + ainner;

  // ---- compute-side indices ----
  int l16 = lane & 15, lq = lane >> 4;
  int rb = wv & 1, cb = wv >> 1;
  int xrow = rb * 16 + l16;        // token row (MFMA A-operand)
  int arow = cb * 16 + l16;        // rank row  (MFMA B-operand)
  int swx = (xrow & 7) << 4;
  int swa = (arow & 7) << 4;

  f32x4 acc = {0.f, 0.f, 0.f, 0.f};

  // prologue: stage steps 0,1,2
#pragma unroll
  for (int p = 0; p < 3; ++p) {
    gll16(xsrc + (size_t)p * 256, &lds[p][wv * 1024]);
    gll16(asrc + (size_t)p * 128, &lds[p][8192 + wv * 1024]);
  }

  for (int t = 0; t < NT; ++t) {
    if (t < NT - 2)       asm volatile("s_waitcnt vmcnt(4)" ::: "memory");
    else if (t == NT - 2) asm volatile("s_waitcnt vmcnt(2)" ::: "memory");
    else                  asm volatile("s_waitcnt vmcnt(0)" ::: "memory");
    __builtin_amdgcn_s_barrier();
    asm volatile("" ::: "memory");
    if (t + 3 < NT) {
      char* nbuf = lds[(t + 3) & 3];
      gll16(xsrc + (size_t)(t + 3) * 256, nbuf + wv * 1024);
      gll16(asrc + (size_t)(t + 3) * 128, nbuf + 8192 + wv * 1024);
    }
    const char* cbuf = lds[t & 3];
#pragma unroll
    for (int m = 0; m < 2; ++m) {
      f32x4 xv0 = *(const f32x4*)(cbuf + xrow * 256 + ((m * 128 + lq * 32) ^ swx));
      f32x4 xv1 = *(const f32x4*)(cbuf + xrow * 256 + ((m * 128 + lq * 32 + 16) ^ swx));
      bf16x8 xf = { (__bf16)xv0[0], (__bf16)xv0[1], (__bf16)xv0[2], (__bf16)xv0[3],
                    (__bf16)xv1[0], (__bf16)xv1[1], (__bf16)xv1[2], (__bf16)xv1[3] };
      bf16x8 af = *(const bf16x8*)(cbuf + 8192 + arow * 128 + ((m * 64 + lq * 16) ^ swa));
      acc = __builtin_amdgcn_mfma_f32_16x16x32_bf16(xf, af, acc, 0, 0, 0);
    }
    asm volatile("" ::: "memory");
  }

  float* xo = xap + (size_t)ks * T_TOK * RANK;
#pragma unroll
  for (int j = 0; j < 4; ++j) {
    int tr = rb * 16 + lq * 4 + j;
    if (tr < nv) {
      int tk = perm[start + tr];
      xo[(size_t)tk * RANK + cb * 16 + l16] = acc[j];
    }
  }
}

// ---------------- reduce partials -> bf16 xa ----------------
__global__ __launch_bounds__(256) void reduce_xa(const float* __restrict__ xap,
                                                 __bf16* __restrict__ xa) {
  int i = blockIdx.x * 256 + threadIdx.x;          // 131072 float4 groups
  const float4* p = (const float4*)xap;
  float4 s = p[i];
#pragma unroll
  for (int ks = 1; ks < KSPLIT; ++ks) {
    float4 q = p[(size_t)ks * (T_TOK * RANK / 4) + i];
    s.x += q.x; s.y += q.y; s.z += q.z; s.w += q.w;
  }
  bf16x4 o = { (__bf16)s.x, (__bf16)s.y, (__bf16)s.z, (__bf16)s.w };
  ((bf16x4*)xa)[i] = o;
}

// ---------------- stage 1 fallback (no split-K) — used only if ws too small ----------------
__global__ __launch_bounds__(512) void stage1f(const float* __restrict__ x,
    const __bf16* __restrict__ Abf, const int* __restrict__ tinfo,
    const int* __restrict__ ntilesp, const int* __restrict__ perm,
    __bf16* __restrict__ xa) {
  int b = blockIdx.x;
  if (b >= *ntilesp) return;
  int a = tinfo[b * 3], start = tinfo[b * 3 + 1], nv = tinfo[b * 3 + 2];
  int tid = threadIdx.x, lane = tid & 63, w = tid >> 6;
  int rb = w & 1, cb = w >> 1;
  int l16 = lane & 15, lq = lane >> 4;
  int trow = rb * 16 + l16;
  int tok = (trow < nv) ? perm[start + trow] : 0;
  const float*  xrow = x + (size_t)tok * DIN + lq * 8;
  const __bf16* arow = Abf + (size_t)(a * RANK + cb * 16 + l16) * DIN + lq * 8;
  f32x4 acc = {0.f, 0.f, 0.f, 0.f};
#pragma unroll 4
  for (int k0 = 0; k0 < DIN; k0 += 32) {
    float4 v0 = *(const float4*)(xrow + k0);
    float4 v1 = *(const float4*)(xrow + k0 + 4);
    bf16x8 af = CVT8(v0, v1);
    bf16x8 bfr = *(const bf16x8*)(arow + k0);
    acc = __builtin_amdgcn_mfma_f32_16x16x32_bf16(af, bfr, acc, 0, 0, 0);
  }
#pragma unroll
  for (int j = 0; j < 4; ++j) {
    int tr = rb * 16 + lq * 4 + j;
    if (tr < nv) {
      int tk = perm[start + tr];
      xa[(size_t)tk * RANK + cb * 16 + l16] = (__bf16)acc[j];
    }
  }
}

// ---------------- stage 2 (quad-buffered depth-3 pipeline): out = base + 2 * xa * B_a ----------
// grid (DSPLIT, MAXTILES), block 512 (8 waves). NS=8 steps of 64 d; same schedule as stage1s.
// Results held in res[NS] (statically indexed under full unroll); ALL stores in epilogue so the
// in-loop VMEM queue stays pure loads (loads/stores retire out of order on CDNA — round-6 lesson).
__global__ __launch_bounds__(512) void stage2(const __bf16* __restrict__ xa,
    const __bf16* __restrict__ Bt, const float* __restrict__ base,
    const int* __restrict__ tinfo, const int* __restrict__ ntilesp,
    const int* __restrict__ perm, float* __restrict__ out) {
  __shared__ char lds[4][16384];   // per buf: [0,8192) = base tile, [8192,16384) = Bt tile
  int b = blockIdx.y;
  if (b >= *ntilesp) return;       // uniform
  int a = tinfo[b * 3], start = tinfo[b * 3 + 1], nv = tinfo[b * 3 + 2];
  int tid = threadIdx.x, lane = tid & 63, wv = tid >> 6;
  int dblk = blockIdx.x * DCH;

  // ---- staging addresses (advance by step) ----
  int brow = wv * 4 + (lane >> 4);                     // base-tile token row 0..31
  int btok = (brow < nv) ? perm[start + brow] : perm[start];
  int binner = ((lane & 15) * 16) ^ ((brow & 7) << 4);
  const char* bsrc = (const char*)(base + (size_t)btok * DOUT + dblk) + binner;
  int trow = wv * 8 + (lane >> 3);                     // Bt-tile d row 0..63
  int tinner = ((lane & 7) * 16) ^ ((trow & 7) << 4);
  const char* tsrc = (const char*)(Bt + (size_t)(dblk + trow) * TOTR + a * RANK) + tinner;

  // ---- compute mapping: wave -> token half (wv&1), 16-d slice (wv>>1) ----
  int tb = wv & 1, dg = wv >> 1;
  int l16 = lane & 15, lq = lane >> 4;
  int tIdx = tb * 16 + l16;        // token index in tile (C col)
  bool valid = tIdx < nv;
  int token = valid ? perm[start + tIdx] : perm[start];

  // xa fragments (B-operand), fixed for whole block — issued before the prologue stages,
  // so they're older than every staged load (counts stay conservative-safe)
  const __bf16* xrow = xa + (size_t)token * RANK + lq * 8;
  bf16x8 xv0 = *(const bf16x8*)(xrow);
  bf16x8 xv1 = *(const bf16x8*)(xrow + 32);

  float* orow = out + (size_t)token * DOUT + dblk + dg * 16 + lq * 4;

  // LDS read offsets (per-step constant)
  int btrow = dg * 16 + l16;                           // d row in Bt tile
  int btoff0 = btrow * 128 + ((lq * 16) ^ ((btrow & 7) << 4));
  int btoff1 = btrow * 128 + ((lq * 16 + 64) ^ ((btrow & 7) << 4));
  int bsoff  = tIdx * 256 + ((dg * 64 + lq * 16) ^ ((tIdx & 7) << 4));

  f32x4 res[NS];                   // statically indexed under full unroll

  asm volatile("" ::: "memory");
  // prologue: stage steps 0,1,2
#pragma unroll
  for (int p = 0; p < 3; ++p) {
    gll16(bsrc + (size_t)p * 256,   &lds[p][wv * 1024]);
    gll16(tsrc + (size_t)p * 65536, &lds[p][8192 + wv * 1024]);
  }

#pragma unroll
  for (int t = 0; t < NS; ++t) {
    if (t < NS - 2)       asm volatile("s_waitcnt vmcnt(4)" ::: "memory");
    else if (t == NS - 2) asm volatile("s_waitcnt vmcnt(2)" ::: "memory");
    else                  asm volatile("s_waitcnt vmcnt(0)" ::: "memory");
    __builtin_amdgcn_s_barrier();
    asm volatile("" ::: "memory");
    if (t + 3 < NS) {
      char* nbuf = lds[(t + 3) & 3];
      gll16(bsrc + (size_t)(t + 3) * 256,   nbuf + wv * 1024);          // +64 d = 256 B/row
      gll16(tsrc + (size_t)(t + 3) * 65536, nbuf + 8192 + wv * 1024);   // +64 rows * 1024 B
    }
    const char* cbuf = lds[t & 3];
    bf16x8 bf0 = *(const bf16x8*)(cbuf + 8192 + btoff0);
    bf16x8 bf1 = *(const bf16x8*)(cbuf + 8192 + btoff1);
    f32x4  bs  = *(const f32x4*)(cbuf + bsoff);
    f32x4 z = {0.f, 0.f, 0.f, 0.f};
    z = __builtin_amdgcn_mfma_f32_16x16x32_bf16(bf0, xv0, z, 0, 0, 0);
    z = __builtin_amdgcn_mfma_f32_16x16x32_bf16(bf1, xv1, z, 0, 0, 0);
    res[t][0] = bs[0] + 2.0f * z[0];
    res[t][1] = bs[1] + 2.0f * z[1];
    res[t][2] = bs[2] + 2.0f * z[2];
    res[t][3] = bs[3] + 2.0f * z[3];
    asm volatile("" ::: "memory");
  }

  // epilogue: all stores issued here; nothing waits on them inside the loop
  if (valid) {
#pragma unroll
    for (int t = 0; t < NS; ++t)
      *(float4*)(orow + t * 64) = *(const float4*)&res[t];
  }
}

extern "C" void kernel_launch(void* const* d_in, const int* in_sizes, int n_in,
                              void* d_out, int out_size, void* d_ws, size_t ws_size,
                              hipStream_t stream) {
  const float* x   = (const float*)d_in[0];
  const float* A   = (const float*)d_in[1];
  const float* B   = (const float*)d_in[2];
  const float* bas = (const float*)d_in[3];
  const int*   ids = (const int*)d_in[4];
  float* out = (float*)d_out;
  char* ws = (char*)d_ws;
  int* cursors = (int*)(ws + WS_CURSORS);
  int* ntiles  = (int*)(ws + WS_NTILES);
  int* flag    = (int*)(ws + WS_FLAG);
  int* tinfo   = (int*)(ws + WS_TINFO);
  int* perm    = (int*)(ws + WS_PERM);
  __bf16* xa   = (__bf16*)(ws + WS_XA);
  __bf16* Abf  = (__bf16*)(ws + WS_ABF);
  __bf16* Bt   = (__bf16*)(ws + WS_BT);
  float*  xap  = (float*)(ws + WS_XAP);

  hist_prep<<<1, 1024, 0, stream>>>(ids, cursors, ntiles, flag, tinfo);
  scatter_k<<<T_TOK / 256, 256, 0, stream>>>(ids, flag, cursors, perm);
  prep_ab<<<2048 + 512, 256, 0, stream>>>(A, Abf, B, Bt);
  if (ws_size >= WS_END) {
    stage1s<<<dim3(MAXTILES, KSPLIT), 512, 0, stream>>>(x, Abf, tinfo, ntiles, perm, xap);
    reduce_xa<<<(T_TOK * RANK / 4) / 256, 256, 0, stream>>>(xap, xa);
  } else {
    stage1f<<<MAXTILES, 512, 0, stream>>>(x, Abf, tinfo, ntiles, perm, xa);
  }
  stage2<<<dim3(DSPLIT, MAXTILES), 512, 0, stream>>>(xa, Bt, bas, tinfo, ntiles, perm, out);
}

// Round 9
// 145.431 us; speedup vs baseline: 1.0255x; 1.0255x over previous
//
#include <hip/hip_runtime.h>
#include <hip/hip_bf16.h>

#define T_TOK 8192
#define DIN   4096
#define DOUT  4096
#define RANK  64
#define NAD   8
#define TS    64          // tokens per tile (supertile: halves A/Bt re-staging vs 32)
#define MAXTILES 135      // sum ceil(count_a/TS) <= 128+7
#define TOTR  (NAD*RANK)  // 512
#define KSPLIT 4
#define KCH   (DIN / KSPLIT)   // 1024
#define NT    (KCH / 64)       // 16 K-steps of BK=64
#define DSPLIT 16
#define DCH   (DOUT / DSPLIT)  // 256
#define NS    (DCH / 64)       // 4 d-steps of 64

typedef __bf16 bf16x8 __attribute__((ext_vector_type(8)));
typedef __bf16 bf16x4 __attribute__((ext_vector_type(4)));
typedef float  f32x4  __attribute__((ext_vector_type(4)));

// ---- workspace layout (bytes) ----
#define WS_NTILES  64        // 1 int
#define WS_TINFO   256       // MAXTILES*3 int
#define WS_PERM    4096      // 8192 int
#define WS_XA      0x10000   // 8192*64 bf16 (1 MB)
#define WS_ABF     0x110000  // 512*4096 bf16 (4 MB)
#define WS_BT      0x510000  // 4096*512 bf16 (4 MB)
#define WS_XAP     0x910000  // KSPLIT*8192*64 fp32 (8 MB)
#define WS_END     (0x910000 + (size_t)KSPLIT * T_TOK * RANK * 4)

__device__ __forceinline__ void gll16(const void* g, void* l) {
  __builtin_amdgcn_global_load_lds(
      (const __attribute__((address_space(1))) unsigned int*)g,
      (__attribute__((address_space(3))) unsigned int*)l, 16, 0, 0);
}

// ---------------- prep: histogram + tile table + scatter (merged, one block) ----------------
__global__ __launch_bounds__(1024) void hist_prep(const int* __restrict__ ids,
    int* __restrict__ ntilesp, int* __restrict__ tinfo, int* __restrict__ perm) {
  __shared__ int cnt[NAD], s_ofs[NAD], s_cur[NAD], s_tbase[NAD + 1];
  __shared__ int s_is64;
  int tid = threadIdx.x, lane = tid & 63;
  if (tid < NAD) cnt[tid] = 0;
  if (tid == 0) s_is64 = 1;
  __syncthreads();
  // int64 detection: values are 0..7, so if data is i64 every odd 32-bit word is 0
  int any = 0;
  for (int i = tid; i < T_TOK; i += 1024)
    if (i & 1) any |= ids[i];
  if (any) s_is64 = 0;
  __syncthreads();
  int is64 = s_is64;
  int loc[NAD];
#pragma unroll
  for (int a = 0; a < NAD; ++a) loc[a] = 0;
  for (int t = tid; t < T_TOK; t += 1024) {
    int id = (is64 ? ids[2 * t] : ids[t]) & 7;
#pragma unroll
    for (int a = 0; a < NAD; ++a) {
      unsigned long long m = __ballot(id == a);
      if (lane == 0) loc[a] += __popcll(m);
    }
  }
  if (lane == 0) {
#pragma unroll
    for (int a = 0; a < NAD; ++a) if (loc[a]) atomicAdd(&cnt[a], loc[a]);
  }
  __syncthreads();
  if (tid == 0) {
    int ofs = 0, tb = 0;
    for (int a = 0; a < NAD; ++a) {
      s_ofs[a] = ofs;
      s_tbase[a] = tb;
      ofs += cnt[a];
      tb += (cnt[a] + TS - 1) / TS;
    }
    s_tbase[NAD] = tb;
    *ntilesp = tb;
  }
  __syncthreads();
  if (tid < NAD) s_cur[tid] = s_ofs[tid];
  int ntt = s_tbase[NAD];
  for (int e = tid; e < ntt; e += 1024) {
    int a = 0;
    while (e >= s_tbase[a + 1]) ++a;
    int t0 = (e - s_tbase[a]) * TS;
    int c = cnt[a];
    tinfo[e * 3 + 0] = a;
    tinfo[e * 3 + 1] = s_ofs[a] + t0;
    tinfo[e * 3 + 2] = (c - t0 < TS) ? (c - t0) : TS;
  }
  __syncthreads();
  // scatter with wave-aggregated LDS-cursor atomics
  unsigned long long lt = (1ull << lane) - 1ull;
  for (int t = tid; t < T_TOK; t += 1024) {
    int id = (is64 ? ids[2 * t] : ids[t]) & 7;
#pragma unroll
    for (int a = 0; a < NAD; ++a) {
      unsigned long long m = __ballot(id == a);
      if (m) {
        int leader = __ffsll((long long)m) - 1;
        int base_a = 0;
        if (lane == leader) base_a = atomicAdd(&s_cur[a], __popcll(m));
        base_a = __shfl(base_a, leader, 64);
        if (id == a) perm[base_a + __popcll(m & lt)] = t;
      }
    }
  }
}

// ---------------- merged prep: A fp32->bf16 (2048 blocks) + B transpose (512 blocks) ------------
__global__ __launch_bounds__(256) void prep_ab(const float* __restrict__ A,
    __bf16* __restrict__ Abf, const float* __restrict__ B, __bf16* __restrict__ Bt) {
  if (blockIdx.x < 2048) {
    int i = blockIdx.x * 256 + threadIdx.x;        // TOTR*DIN/4 elements
    float4 v = ((const float4*)A)[i];
    bf16x4 o = { (__bf16)v.x, (__bf16)v.y, (__bf16)v.z, (__bf16)v.w };
    ((bf16x4*)Abf)[i] = o;
  } else {
    __shared__ float t[64][65];
    int idx = blockIdx.x - 2048;
    int rb = idx & 7, db = idx >> 3;
    int tid = threadIdx.x;
    int c = tid & 63, q = tid >> 6;                // q: 0..3
#pragma unroll
    for (int i = 0; i < 16; ++i) {
      int r = i * 4 + q;
      t[r][c] = B[(size_t)(rb * 64 + r) * DOUT + db * 64 + c];
    }
    __syncthreads();
#pragma unroll
    for (int i = 0; i < 16; ++i) {
      int d = i * 4 + q;
      Bt[(size_t)(db * 64 + d) * TOTR + rb * 64 + c] = (__bf16)t[c][d];
    }
  }
}

#define CVT8(lo, hi) { (__bf16)lo[0], (__bf16)lo[1], (__bf16)lo[2], (__bf16)lo[3], \
                       (__bf16)hi[0], (__bf16)hi[1], (__bf16)hi[2], (__bf16)hi[3] }

// ---------------- stage 1 (split-K, TS=64, LDS double-buffer): xap[ks][tok][rank] ----------------
// grid (MAXTILES, KSPLIT), block 512 (8 waves). 16 K-steps of BK=64.
// Per step: x tile [64tok][64K] f32 (16KB, 2 gll16/wave) + A tile [64r][64K] bf16 (8KB, 1 gll16).
// Pure-load vmcnt queue: steady 6 outstanding -> vmcnt(3). Stores epilogue-only (round-6 lesson).
// Wave mapping: tq=wv&3 (16 tok), rh=wv>>2 (32 r): 4 MFMA/step, acc in 2 f32x4.
__global__ __launch_bounds__(512) void stage1s(const float* __restrict__ x,
    const __bf16* __restrict__ Abf, const int* __restrict__ tinfo,
    const int* __restrict__ ntilesp, const int* __restrict__ perm,
    float* __restrict__ xap) {
  __shared__ char lds[2][24576];   // per buf: [0,16384) x tile, [16384,24576) A tile
  int b = blockIdx.x;
  if (b >= *ntilesp) return;       // uniform
  int ks = blockIdx.y;
  int a = tinfo[b * 3], start = tinfo[b * 3 + 1], nv = tinfo[b * 3 + 2];
  int tid = threadIdx.x, lane = tid & 63, wv = tid >> 6;

  // ---- staging addresses ----
  int xr0 = wv * 4 + (lane >> 4);                      // x rows pass 0: 0..31
  int xr1 = xr0 + 32;                                  // pass 1: 32..63
  int xt0 = (xr0 < nv) ? perm[start + xr0] : perm[start];
  int xt1 = (xr1 < nv) ? perm[start + xr1] : perm[start];
  const char* xs0 = (const char*)(x + (size_t)xt0 * DIN + ks * KCH)
                    + (((lane & 15) * 16) ^ ((xr0 & 7) << 4));
  const char* xs1 = (const char*)(x + (size_t)xt1 * DIN + ks * KCH)
                    + (((lane & 15) * 16) ^ ((xr1 & 7) << 4));
  int ar = wv * 8 + (lane >> 3);                       // A row 0..63
  const char* as = (const char*)(Abf + (size_t)(a * RANK + ar) * DIN + ks * KCH)
                   + (((lane & 7) * 16) ^ ((ar & 7) << 4));

  // ---- compute-side indices ----
  int l16 = lane & 15, lq = lane >> 4;
  int tq = wv & 3, rh = wv >> 2;
  int xrow = tq * 16 + l16;        // token row (MFMA A-operand)
  int swx = (xrow & 7) << 4;
  int arow0 = rh * 32 + l16;       // rank rows (MFMA B-operand), rt=0
  int arow1 = arow0 + 16;          // rt=1 (same &7 -> same swizzle)
  int swa = (arow0 & 7) << 4;

  f32x4 acc0 = {0.f, 0.f, 0.f, 0.f}, acc1 = {0.f, 0.f, 0.f, 0.f};

  // prologue: stage K-step 0 into buf 0
  gll16(xs0, &lds[0][wv * 1024]);
  gll16(xs1, &lds[0][8192 + wv * 1024]);
  gll16(as,  &lds[0][16384 + wv * 1024]);

  for (int t = 0; t < NT; ++t) {
    if (t + 1 < NT) {
      char* nb = lds[(t + 1) & 1];
      gll16(xs0 + (size_t)(t + 1) * 256, nb + wv * 1024);
      gll16(xs1 + (size_t)(t + 1) * 256, nb + 8192 + wv * 1024);
      gll16(as  + (size_t)(t + 1) * 128, nb + 16384 + wv * 1024);
      // pure-load queue: [stage_t x3, stage_{t+1} x3] -> wait the 3 oldest
      asm volatile("s_waitcnt vmcnt(3)" ::: "memory");
    } else {
      asm volatile("s_waitcnt vmcnt(0)" ::: "memory");
    }
    __builtin_amdgcn_s_barrier();
    asm volatile("" ::: "memory");
    const char* cb = lds[t & 1];
#pragma unroll
    for (int m = 0; m < 2; ++m) {
      f32x4 xv0 = *(const f32x4*)(cb + xrow * 256 + ((m * 128 + lq * 32) ^ swx));
      f32x4 xv1 = *(const f32x4*)(cb + xrow * 256 + ((m * 128 + lq * 32 + 16) ^ swx));
      bf16x8 xf = CVT8(xv0, xv1);
      bf16x8 a0 = *(const bf16x8*)(cb + 16384 + arow0 * 128 + ((m * 64 + lq * 16) ^ swa));
      bf16x8 a1 = *(const bf16x8*)(cb + 16384 + arow1 * 128 + ((m * 64 + lq * 16) ^ swa));
      acc0 = __builtin_amdgcn_mfma_f32_16x16x32_bf16(xf, a0, acc0, 0, 0, 0);
      acc1 = __builtin_amdgcn_mfma_f32_16x16x32_bf16(xf, a1, acc1, 0, 0, 0);
    }
    asm volatile("" ::: "memory");
    __builtin_amdgcn_s_barrier();
  }

  float* xo = xap + (size_t)ks * T_TOK * RANK;
#pragma unroll
  for (int j = 0; j < 4; ++j) {
    int tr = tq * 16 + lq * 4 + j;
    if (tr < nv) {
      int tk = perm[start + tr];
      xo[(size_t)tk * RANK + rh * 32 + l16]      = acc0[j];
      xo[(size_t)tk * RANK + rh * 32 + 16 + l16] = acc1[j];
    }
  }
}

// ---------------- reduce partials -> bf16 xa ----------------
__global__ __launch_bounds__(256) void reduce_xa(const float* __restrict__ xap,
                                                 __bf16* __restrict__ xa) {
  int i = blockIdx.x * 256 + threadIdx.x;          // 131072 float4 groups
  const float4* p = (const float4*)xap;
  float4 s = p[i];
#pragma unroll
  for (int ks = 1; ks < KSPLIT; ++ks) {
    float4 q = p[(size_t)ks * (T_TOK * RANK / 4) + i];
    s.x += q.x; s.y += q.y; s.z += q.z; s.w += q.w;
  }
  bf16x4 o = { (__bf16)s.x, (__bf16)s.y, (__bf16)s.z, (__bf16)s.w };
  ((bf16x4*)xa)[i] = o;
}

// ---------------- stage 1 fallback (no split-K, TS=64) — used only if ws too small ----------------
__global__ __launch_bounds__(512) void stage1f(const float* __restrict__ x,
    const __bf16* __restrict__ Abf, const int* __restrict__ tinfo,
    const int* __restrict__ ntilesp, const int* __restrict__ perm,
    __bf16* __restrict__ xa) {
  int b = blockIdx.x;
  if (b >= *ntilesp) return;
  int a = tinfo[b * 3], start = tinfo[b * 3 + 1], nv = tinfo[b * 3 + 2];
  int tid = threadIdx.x, lane = tid & 63, wv = tid >> 6;
  int l16 = lane & 15, lq = lane >> 4;
  int tq = wv & 3, rh = wv >> 2;
  int trow = tq * 16 + l16;
  int tok = (trow < nv) ? perm[start + trow] : perm[start];
  const float*  xr = x + (size_t)tok * DIN + lq * 8;
  const __bf16* a0p = Abf + (size_t)(a * RANK + rh * 32 + l16) * DIN + lq * 8;
  const __bf16* a1p = a0p + (size_t)16 * DIN;
  f32x4 acc0 = {0.f, 0.f, 0.f, 0.f}, acc1 = {0.f, 0.f, 0.f, 0.f};
#pragma unroll 4
  for (int k0 = 0; k0 < DIN; k0 += 32) {
    f32x4 v0 = *(const f32x4*)(xr + k0);
    f32x4 v1 = *(const f32x4*)(xr + k0 + 4);
    bf16x8 xf = CVT8(v0, v1);
    bf16x8 f0 = *(const bf16x8*)(a0p + k0);
    bf16x8 f1 = *(const bf16x8*)(a1p + k0);
    acc0 = __builtin_amdgcn_mfma_f32_16x16x32_bf16(xf, f0, acc0, 0, 0, 0);
    acc1 = __builtin_amdgcn_mfma_f32_16x16x32_bf16(xf, f1, acc1, 0, 0, 0);
  }
#pragma unroll
  for (int j = 0; j < 4; ++j) {
    int tr = tq * 16 + lq * 4 + j;
    if (tr < nv) {
      int tk = perm[start + tr];
      xa[(size_t)tk * RANK + rh * 32 + l16]      = (__bf16)acc0[j];
      xa[(size_t)tk * RANK + rh * 32 + 16 + l16] = (__bf16)acc1[j];
    }
  }
}

// ---------------- stage 2 (TS=64, DSPLIT=16, LDS double-buffer): out = base + 2 * xa * B_a ------
// grid (DSPLIT, MAXTILES), block 512 (8 waves). NS=4 steps of 64 d.
// Per step: base tile [64tok][64d] f32 (16KB, 2 gll16/wave) + Bt tile [64d][64r] bf16 (8KB, 1).
// Swapped-operand MFMA (M=d, N=token): lane owns 1 token x 4 consecutive d -> float4 stores.
// res[NS][2] accumulated in registers; ALL stores in epilogue (pure-load vmcnt queue).
__global__ __launch_bounds__(512) void stage2(const __bf16* __restrict__ xa,
    const __bf16* __restrict__ Bt, const float* __restrict__ base,
    const int* __restrict__ tinfo, const int* __restrict__ ntilesp,
    const int* __restrict__ perm, float* __restrict__ out) {
  __shared__ char lds[2][24576];   // per buf: [0,16384) base tile, [16384,24576) Bt tile
  int b = blockIdx.y;
  if (b >= *ntilesp) return;       // uniform
  int a = tinfo[b * 3], start = tinfo[b * 3 + 1], nv = tinfo[b * 3 + 2];
  int tid = threadIdx.x, lane = tid & 63, wv = tid >> 6;
  int dblk = blockIdx.x * DCH;

  // ---- staging addresses ----
  int br0 = wv * 4 + (lane >> 4), br1 = br0 + 32;      // base-tile token rows
  int bt0 = (br0 < nv) ? perm[start + br0] : perm[start];
  int bt1 = (br1 < nv) ? perm[start + br1] : perm[start];
  const char* bs0 = (const char*)(base + (size_t)bt0 * DOUT + dblk)
                    + (((lane & 15) * 16) ^ ((br0 & 7) << 4));
  const char* bs1 = (const char*)(base + (size_t)bt1 * DOUT + dblk)
                    + (((lane & 15) * 16) ^ ((br1 & 7) << 4));
  int trw = wv * 8 + (lane >> 3);                      // Bt-tile d row 0..63
  const char* ts = (const char*)(Bt + (size_t)(dblk + trw) * TOTR + a * RANK)
                   + (((lane & 7) * 16) ^ ((trw & 7) << 4));

  // ---- compute mapping: tq=wv&3 (16 tok), dh=wv>>2 (32 d) ----
  int l16 = lane & 15, lq = lane >> 4;
  int tq = wv & 3, dh = wv >> 2;
  int tIdx = tq * 16 + l16;        // token index in tile (C col)
  bool valid = tIdx < nv;
  int token = valid ? perm[start + tIdx] : perm[start];

  // xa fragments (B-operand), fixed for whole block
  const __bf16* xrow = xa + (size_t)token * RANK + lq * 8;
  bf16x8 xv0 = *(const bf16x8*)(xrow);
  bf16x8 xv1 = *(const bf16x8*)(xrow + 32);

  int swt = (tIdx & 7) << 4;
  int btr0 = dh * 32 + l16, btr1 = btr0 + 16;          // d rows (same &7 -> same swizzle)
  int swb = (btr0 & 7) << 4;

  f32x4 res[NS][2];                // statically indexed under full unroll

  asm volatile("" ::: "memory");
  // prologue: stage step 0 into buf 0
  gll16(bs0, &lds[0][wv * 1024]);
  gll16(bs1, &lds[0][8192 + wv * 1024]);
  gll16(ts,  &lds[0][16384 + wv * 1024]);

#pragma unroll
  for (int t = 0; t < NS; ++t) {
    if (t + 1 < NS) {
      char* nb = lds[(t + 1) & 1];
      gll16(bs0 + (size_t)(t + 1) * 256,   nb + wv * 1024);            // +64 d
      gll16(bs1 + (size_t)(t + 1) * 256,   nb + 8192 + wv * 1024);
      gll16(ts  + (size_t)(t + 1) * 65536, nb + 16384 + wv * 1024);    // +64 Bt rows
      asm volatile("s_waitcnt vmcnt(3)" ::: "memory");
    } else {
      asm volatile("s_waitcnt vmcnt(0)" ::: "memory");
    }
    __builtin_amdgcn_s_barrier();
    asm volatile("" ::: "memory");
    const char* cb = lds[t & 1];
#pragma unroll
    for (int dt = 0; dt < 2; ++dt) {
      int btr = dt ? btr1 : btr0;
      bf16x8 bf0 = *(const bf16x8*)(cb + 16384 + btr * 128 + ((lq * 16) ^ swb));
      bf16x8 bf1 = *(const bf16x8*)(cb + 16384 + btr * 128 + ((lq * 16 + 64) ^ swb));
      f32x4  bs  = *(const f32x4*)(cb + tIdx * 256 + ((dh * 128 + dt * 64 + lq * 16) ^ swt));
      f32x4 z = {0.f, 0.f, 0.f, 0.f};
      z = __builtin_amdgcn_mfma_f32_16x16x32_bf16(bf0, xv0, z, 0, 0, 0);
      z = __builtin_amdgcn_mfma_f32_16x16x32_bf16(bf1, xv1, z, 0, 0, 0);
      res[t][dt][0] = bs[0] + 2.0f * z[0];
      res[t][dt][1] = bs[1] + 2.0f * z[1];
      res[t][dt][2] = bs[2] + 2.0f * z[2];
      res[t][dt][3] = bs[3] + 2.0f * z[3];
    }
    asm volatile("" ::: "memory");
    __builtin_amdgcn_s_barrier();
  }

  // epilogue: all stores here; nothing waits on them inside the loop
  if (valid) {
    float* orow = out + (size_t)token * DOUT + dblk;
#pragma unroll
    for (int t = 0; t < NS; ++t)
#pragma unroll
      for (int dt = 0; dt < 2; ++dt)
        *(float4*)(orow + t * 64 + dh * 32 + dt * 16 + lq * 4) = *(const float4*)&res[t][dt];
  }
}

extern "C" void kernel_launch(void* const* d_in, const int* in_sizes, int n_in,
                              void* d_out, int out_size, void* d_ws, size_t ws_size,
                              hipStream_t stream) {
  const float* x   = (const float*)d_in[0];
  const float* A   = (const float*)d_in[1];
  const float* B   = (const float*)d_in[2];
  const float* bas = (const float*)d_in[3];
  const int*   ids = (const int*)d_in[4];
  float* out = (float*)d_out;
  char* ws = (char*)d_ws;
  int* ntiles  = (int*)(ws + WS_NTILES);
  int* tinfo   = (int*)(ws + WS_TINFO);
  int* perm    = (int*)(ws + WS_PERM);
  __bf16* xa   = (__bf16*)(ws + WS_XA);
  __bf16* Abf  = (__bf16*)(ws + WS_ABF);
  __bf16* Bt   = (__bf16*)(ws + WS_BT);
  float*  xap  = (float*)(ws + WS_XAP);

  hist_prep<<<1, 1024, 0, stream>>>(ids, ntiles, tinfo, perm);
  prep_ab<<<2048 + 512, 256, 0, stream>>>(A, Abf, B, Bt);
  if (ws_size >= WS_END) {
    stage1s<<<dim3(MAXTILES, KSPLIT), 512, 0, stream>>>(x, Abf, tinfo, ntiles, perm, xap);
    reduce_xa<<<(T_TOK * RANK / 4) / 256, 256, 0, stream>>>(xap, xa);
  } else {
    stage1f<<<MAXTILES, 512, 0, stream>>>(x, Abf, tinfo, ntiles, perm, xa);
  }
  stage2<<<dim3(DSPLIT, MAXTILES), 512, 0, stream>>>(xa, Bt, bas, tinfo, ntiles, perm, out);
}